// Round 5
// baseline (484.551 us; speedup 1.0000x reference)
//
#include <hip/hip_runtime.h>
#include <hip/hip_bf16.h>

typedef float  f32x4 __attribute__((ext_vector_type(4)));
typedef short  s16x8 __attribute__((ext_vector_type(8)));

#define MEMH   256        // mem_dim
#define MSGD   512        // msg_dim
#define G3     768        // 3*H
#define W_IH_ELEMS (G3*MSGD)        // 393216
#define W_HH_ELEMS (G3*MEMH)        // 196608
#define W_TOT_ELEMS (W_IH_ELEMS + W_HH_ELEMS)  // 589824
#define W_BYTES    ((size_t)W_TOT_ELEMS * 2)   // 1179648

#define BM     64         // rows per block
#define NTHR   1024       // 16 waves
#define AH_OFF 0          // A_h: 64x256 bf16, pitch 512 B  -> 32768 B
#define AM_OFF 32768      // A_msg: 64x512 bf16, pitch 1024 B -> 65536 B
#define O_OFF  32768      // O fp32 64x260 (pitch 1040 B) reuses A_msg region
#define LDS_BYTES (32768 + 66560)   // 99328

static __device__ __forceinline__ short f2bf(float x) {
    __hip_bfloat16 b = __float2bfloat16(x);
    return __builtin_bit_cast(short, b);
}
static __device__ __forceinline__ float bf2f(short s) {
    unsigned int u = ((unsigned int)(unsigned short)s) << 16;
    return __builtin_bit_cast(float, u);
}
static __device__ __forceinline__ float sigf(float x) {
    return 1.f / (1.f + __expf(-x));
}
static __device__ __forceinline__ float tanh_fast(float x) {
    float e = __expf(-2.f * fabsf(x));
    float t = (1.f - e) / (1.f + e);
    return copysignf(t, x);
}
static __device__ __forceinline__ f32x4 ntload4(const float* p) {
    return __builtin_nontemporal_load((const f32x4*)p);
}
static __device__ __forceinline__ void ntstore4(float* p, f32x4 v) {
    __builtin_nontemporal_store(v, (f32x4*)p);
}

// ---------------------------------------------------------------- copy kernel (fallback path only)
__global__ void smu_copy_kernel(const float* __restrict__ mem,
                                const float* __restrict__ lu,
                                float* __restrict__ out_mem,
                                float* __restrict__ out_lu,
                                long n_mem4, long n_lu4) {
    long i = (long)blockIdx.x * blockDim.x + threadIdx.x;
    long stride = (long)gridDim.x * blockDim.x;
    long total = n_mem4 + n_lu4;
    for (; i < total; i += stride) {
        if (i < n_mem4) ntstore4(out_mem + i * 4, ntload4(mem + i * 4));
        else {
            long j = (i - n_mem4) * 4;
            ntstore4(out_lu + j, ntload4(lu + j));
        }
    }
}

// --------------------------------------------------- weight fp32->bf16 PACKED fragment layout
// ih: frag (t in [0,48), k in [0,16)) at elem off (t*16+k)*512; within frag
// elem idx = l*8+e  ->  source row t*16+(l&15), col k*32+(l>>4)*8+e.
// hh: frag (t in [0,48), k in [0,8)) at W_IH_ELEMS + (t*8+k)*512, same inner map.
__global__ void smu_cvtw_kernel(const float* __restrict__ wih,
                                const float* __restrict__ whh,
                                short* __restrict__ o) {
    int i = blockIdx.x * blockDim.x + threadIdx.x;
    if (i >= W_TOT_ELEMS) return;
    if (i < W_IH_ELEMS) {
        int f = i >> 9, r = i & 511, l = r >> 3, e = r & 7;
        int t = f >> 4, k = f & 15;
        int row = t * 16 + (l & 15), col = k * 32 + (l >> 4) * 8 + e;
        o[i] = f2bf(wih[row * MSGD + col]);
    } else {
        int j = i - W_IH_ELEMS;
        int f = j >> 9, r = j & 511, l = r >> 3, e = r & 7;
        int t = f >> 3, k = f & 7;
        int row = t * 16 + (l & 15), col = k * 32 + (l >> 4) * 8 + e;
        o[i] = f2bf(whh[row * MEMH + col]);
    }
}

// --------------------------------------------------- bitmap of updated ids
__global__ void smu_bits_kernel(const int* __restrict__ ids,
                                unsigned* __restrict__ bm, int n) {
    int i = blockIdx.x * blockDim.x + threadIdx.x;
    if (i < n) {
        int id = ids[i];
        atomicOr(&bm[id >> 5], 1u << (id & 31));
    }
}

// ------------------------------------------------------------ B-frag loader
// packed path: one contiguous 1KB wave load. fallback: scattered f32 converts.
template<bool USE_WS>
static __device__ __forceinline__ s16x8 load_b(const float* __restrict__ Wf,
                                               const short* __restrict__ Wb,
                                               int t, int k, int ldk, int nkt, int lane) {
    if constexpr (USE_WS) {
        return *(const s16x8*)(Wb + ((size_t)(t * nkt + k) << 9) + lane * 8);
    } else {
        int row = t * 16 + (lane & 15);
        int col = k * 32 + (lane >> 4) * 8;
        f32x4 x = *(const f32x4*)(Wf + (size_t)row * ldk + col);
        f32x4 y = *(const f32x4*)(Wf + (size_t)row * ldk + col + 4);
        s16x8 s;
        s[0]=f2bf(x[0]); s[1]=f2bf(x[1]); s[2]=f2bf(x[2]); s[3]=f2bf(x[3]);
        s[4]=f2bf(y[0]); s[5]=f2bf(y[1]); s[6]=f2bf(y[2]); s[7]=f2bf(y[3]);
        return s;
    }
}

// copy-pipe: 4 in-flight batches of 2 rows each (depth-4: load at step s,
// store at step s+4). 32 rows/wave, loaded over the 16 GEMM1 steps, stores
// drain during GEMM2 steps 0..3. Arrays indexed by (s & 3): compile-time
// constant after full unroll -> registers, no scratch.
#define CP_LOAD(S) do { if constexpr (FUSED) {                                        \
    const int s_ = (S);                                                               \
    if (s_ >= 0 && s_ < 16) {                                                         \
        const int  lo_ = s_ * 2;                                                      \
        const long o0_ = (long)w * 32 + lo_;                                          \
        const long r0_ = crow_base + o0_;                                             \
        const int  bi_ = s_ & 3;                                                      \
        cpf[bi_][0] = (o0_ < cpslab) && (r0_ < n_nodes) && !((cpwin >> lo_) & 1);     \
        cpf[bi_][1] = (o0_ + 1 < cpslab) && (r0_ + 1 < n_nodes) && !((cpwin >> (lo_ + 1)) & 1); \
        if (cpf[bi_][0]) cpv[bi_][0] = ntload4(memory + r0_ * MEMH + (lane << 2));    \
        if (cpf[bi_][1]) cpv[bi_][1] = ntload4(memory + (r0_ + 1) * MEMH + (lane << 2)); \
    } } } while (0)

#define CP_STORE(S) do { if constexpr (FUSED) {                                       \
    const int s_ = (S);                                                               \
    if (s_ >= 0 && s_ < 16) {                                                         \
        const long r0_ = crow_base + (long)w * 32 + s_ * 2;                           \
        const int  bi_ = s_ & 3;                                                      \
        if (cpf[bi_][0]) ntstore4(out_mem + r0_ * MEMH + (lane << 2), cpv[bi_][0]);   \
        if (cpf[bi_][1]) ntstore4(out_mem + (r0_ + 1) * MEMH + (lane << 2), cpv[bi_][1]); \
        cpf[bi_][0] = false; cpf[bi_][1] = false;                                     \
    } } } while (0)

// --------------------------------------------------------------- fused GRU+LN+copy
// Block: 1024 threads (16 waves), BM=64 rows. Wave w owns gate-tiles
// t = w+16i (i = r,z,n). Accs: acc[m][0]=r-sum, acc[m][1]=z-sum,
// acc[m][2]=gi_n, accn[m]=gh_n  (GEMM2 adds r,z into acc[m][0..1]).
// Copy of non-updated memory rows pipelined (depth 4) through GEMM1.
template<bool USE_WS, bool FUSED>
__global__ __launch_bounds__(NTHR, 1)
void smu_gru_kernel(const int*   __restrict__ ids,
                    const float* __restrict__ msg,
                    const float* __restrict__ ts,
                    const float* __restrict__ memory,
                    const float* __restrict__ lu,
                    const float* __restrict__ W_ih,
                    const float* __restrict__ W_hh,
                    const float* __restrict__ b_ih,
                    const float* __restrict__ b_hh,
                    const float* __restrict__ gamma,
                    const float* __restrict__ beta,
                    const short* __restrict__ wsw,
                    const unsigned* __restrict__ bm,
                    float* __restrict__ out_mem,
                    float* __restrict__ out_lu,
                    long n_nodes, long cpslab) {
    __shared__ __align__(16) unsigned char lds[LDS_BYTES];
    const int tid  = threadIdx.x;
    const int bid  = blockIdx.x;
    const long base = (long)bid * BM;
    const long crow_base = (long)bid * cpslab;

    // ---- stage A_msg: 64x512 f32 -> bf16 (4096 8-elem units, 4/thread)
    {
        const float* src = msg + base * MSGD;
        #pragma unroll
        for (int it = 0; it < 4; ++it) {
            int u = tid + NTHR * it;         // 0..4095
            int row = u >> 6;                // 64 units per row
            f32x4 a = ntload4(src + u * 8);
            f32x4 b = ntload4(src + u * 8 + 4);
            s16x8 s;
            s[0]=f2bf(a[0]); s[1]=f2bf(a[1]); s[2]=f2bf(a[2]); s[3]=f2bf(a[3]);
            s[4]=f2bf(b[0]); s[5]=f2bf(b[1]); s[6]=f2bf(b[2]); s[7]=f2bf(b[3]);
            int byte = AM_OFF + ((u * 16) ^ ((row & 7) << 4));
            *(s16x8*)(lds + byte) = s;
        }
        // ---- stage A_h (gather): 64x256 (2048 units, 2/thread)
        #pragma unroll
        for (int it = 0; it < 2; ++it) {
            int u = tid + NTHR * it;         // 0..2047
            int row = u >> 5;                // 32 units per row
            int c8  = u & 31;
            int id  = ids[base + row];
            const float* hs = memory + (size_t)id * MEMH + c8 * 8;
            f32x4 a = ntload4(hs);
            f32x4 b = ntload4(hs + 4);
            s16x8 s;
            s[0]=f2bf(a[0]); s[1]=f2bf(a[1]); s[2]=f2bf(a[2]); s[3]=f2bf(a[3]);
            s[4]=f2bf(b[0]); s[5]=f2bf(b[1]); s[6]=f2bf(b[2]); s[7]=f2bf(b[3]);
            int byte = AH_OFF + ((u * 16) ^ ((row & 7) << 4));
            *(s16x8*)(lds + byte) = s;
        }
    }
    __syncthreads();

    const int lane = tid & 63;
    const int w    = tid >> 6;              // 0..15
    const int lr   = lane & 15;
    const int lk8  = (lane >> 4) * 8;       // k offset within 32-wide ktile
    const int sw   = (lr & 7) << 4;
    const short* Wi = wsw;
    const short* Wh = wsw + W_IH_ELEMS;

    // ---- copy-pipe state + per-wave 32-bit skip window (all 16 waves copy)
    f32x4 cpv[4][2];
    bool  cpf[4][2] = {{false,false},{false,false},{false,false},{false,false}};
    unsigned long long cpwin = 0;
    if constexpr (FUSED) {
        long start = crow_base + (long)w * 32;
        long wi = start >> 5;
        int  off = (int)(start & 31);
        unsigned b0 = bm[wi], b1 = bm[wi + 1];    // bm is padded
        cpwin = (((unsigned long long)b1 << 32) | b0) >> off;
    }

    f32x4 acc[4][3] = {};   // [m][0]=r-sum  [1]=z-sum  [2]=gi_n
    f32x4 accn[4]   = {};   // gh_n

    // ---- GEMM 1: msg @ W_ih^T  (K=512, 16 ktiles; copy pipe runs here)
    {
        s16x8 b[2][3];
        #pragma unroll
        for (int i = 0; i < 3; ++i) b[0][i] = load_b<USE_WS>(W_ih, Wi, w + 16*i, 0, MSGD, 16, lane);
        #pragma unroll
        for (int i = 0; i < 3; ++i) b[1][i] = load_b<USE_WS>(W_ih, Wi, w + 16*i, 1, MSGD, 16, lane);
        #pragma unroll
        for (int k = 0; k < 16; ++k) {
            CP_STORE(k - 4);
            CP_LOAD(k);
            const int cb = (k * 32 + lk8) * 2;
            #pragma unroll
            for (int m = 0; m < 4; ++m) {
                s16x8 a = *(const s16x8*)(lds + AM_OFF + (((m*16 + lr) * 1024 + cb) ^ sw));
                #pragma unroll
                for (int i = 0; i < 3; ++i)
                    acc[m][i] = __builtin_amdgcn_mfma_f32_16x16x32_bf16(a, b[k & 1][i], acc[m][i], 0, 0, 0);
            }
            if (k < 14) {
                #pragma unroll
                for (int i = 0; i < 3; ++i)
                    b[k & 1][i] = load_b<USE_WS>(W_ih, Wi, w + 16*i, k + 2, MSGD, 16, lane);
            }
        }
    }
    // ---- GEMM 2: h @ W_hh^T  (K=256, 8 ktiles; copy stores drain in steps 0..3)
    {
        s16x8 b[2][3];
        #pragma unroll
        for (int i = 0; i < 3; ++i) b[0][i] = load_b<USE_WS>(W_hh, Wh, w + 16*i, 0, MEMH, 8, lane);
        #pragma unroll
        for (int i = 0; i < 3; ++i) b[1][i] = load_b<USE_WS>(W_hh, Wh, w + 16*i, 1, MEMH, 8, lane);
        #pragma unroll
        for (int k = 0; k < 8; ++k) {
            CP_STORE(12 + k);   // stores batches 12..15 during k=0..3, no-op after
            const int cb = (k * 32 + lk8) * 2;
            #pragma unroll
            for (int m = 0; m < 4; ++m) {
                s16x8 a = *(const s16x8*)(lds + AH_OFF + (((m*16 + lr) * 512 + cb) ^ sw));
                acc[m][0] = __builtin_amdgcn_mfma_f32_16x16x32_bf16(a, b[k & 1][0], acc[m][0], 0, 0, 0);
                acc[m][1] = __builtin_amdgcn_mfma_f32_16x16x32_bf16(a, b[k & 1][1], acc[m][1], 0, 0, 0);
                accn[m]   = __builtin_amdgcn_mfma_f32_16x16x32_bf16(a, b[k & 1][2], accn[m],   0, 0, 0);
            }
            if (k < 6) {
                #pragma unroll
                for (int i = 0; i < 3; ++i)
                    b[k & 1][i] = load_b<USE_WS>(W_hh, Wh, w + 16*i, k + 2, MEMH, 8, lane);
            }
        }
    }

    __syncthreads();   // all A_msg reads done before O overwrites region

    // ---- gate epilogue: C layout col=lane&15, row=(lane>>4)*4+q
    {
        const int lq = (lane >> 4) * 4;
        const int j  = w * 16 + lr;          // this lane's output column
        const float br = b_ih[j]       + b_hh[j];
        const float bz = b_ih[256 + j] + b_hh[256 + j];
        const float bihn = b_ih[512 + j], bhhn = b_hh[512 + j];
        #pragma unroll
        for (int m = 0; m < 4; ++m) {
            #pragma unroll
            for (int q = 0; q < 4; ++q) {
                int row = m * 16 + lq + q;
                float r = sigf(acc[m][0][q] + br);
                float z = sigf(acc[m][1][q] + bz);
                float n = tanh_fast(acc[m][2][q] + bihn + r * (accn[m][q] + bhhn));
                float hv = bf2f(*(const short*)(lds + AH_OFF + ((row * 512 + j * 2) ^ ((row & 7) << 4))));
                float o = (1.f - z) * n + z * hv;
                *(float*)(lds + O_OFF + (row * 260 + j) * 4) = o;
            }
        }
    }
    __syncthreads();

    // ---- LayerNorm + scatter: wave w handles rows 4w..4w+3
    #pragma unroll
    for (int rr = 0; rr < 4; ++rr) {
        int row = w * 4 + rr;
        f32x4 x = *(const f32x4*)(lds + O_OFF + (row * 260 + lane * 4) * 4);
        float s1 = x[0] + x[1] + x[2] + x[3];
        float s2 = x[0]*x[0] + x[1]*x[1] + x[2]*x[2] + x[3]*x[3];
        #pragma unroll
        for (int mm = 32; mm > 0; mm >>= 1) {
            s1 += __shfl_xor(s1, mm);
            s2 += __shfl_xor(s2, mm);
        }
        float mu  = s1 * (1.f / 256.f);
        float var = fmaxf(s2 * (1.f / 256.f) - mu * mu, 0.f);
        float inv = rsqrtf(var + 1e-5f);
        f32x4 g  = *(const f32x4*)(gamma + lane * 4);
        f32x4 be = *(const f32x4*)(beta  + lane * 4);
        int id = ids[base + row];
        f32x4 y;
        #pragma unroll
        for (int c = 0; c < 4; ++c) y[c] = (x[c] - mu) * inv * g[c] + be[c];
        ntstore4(out_mem + (size_t)id * MEMH + lane * 4, y);
        if (lane == 0) __builtin_nontemporal_store(ts[base + row], out_lu + id);
    }

    // ---- tails: rows beyond the 512-row pipeline capacity (normally none) + last_update
    if constexpr (FUSED) {
        for (long o = 512 + w; o < cpslab; o += 16) {
            long row = crow_base + o;
            if (row < n_nodes && !((bm[row >> 5] >> (row & 31)) & 1u)) {
                f32x4 v = ntload4(memory + row * MEMH + (lane << 2));
                ntstore4(out_mem + row * MEMH + (lane << 2), v);
            }
        }
        for (long i = (long)bid * NTHR + tid; i < n_nodes; i += (long)gridDim.x * NTHR) {
            if (!((bm[i >> 5] >> (i & 31)) & 1u)) {
                float v = __builtin_nontemporal_load(lu + i);
                __builtin_nontemporal_store(v, out_lu + i);
            }
        }
    }
}

// ------------------------------------------------------------------- launcher
extern "C" void kernel_launch(void* const* d_in, const int* in_sizes, int n_in,
                              void* d_out, int out_size, void* d_ws, size_t ws_size,
                              hipStream_t stream) {
    (void)n_in; (void)out_size;
    const int*   ids = (const int*)  d_in[0];
    const float* msg = (const float*)d_in[1];
    const float* ts  = (const float*)d_in[2];
    const float* mem = (const float*)d_in[3];
    const float* lu  = (const float*)d_in[4];
    const float* Wih = (const float*)d_in[5];
    const float* Whh = (const float*)d_in[6];
    const float* bih = (const float*)d_in[7];
    const float* bhh = (const float*)d_in[8];
    const float* gam = (const float*)d_in[9];
    const float* bet = (const float*)d_in[10];

    const int  n_upd   = in_sizes[0];                 // 65536
    const long n_nodes = (long)in_sizes[3] / MEMH;    // 500000

    float* out_mem = (float*)d_out;
    float* out_lu  = out_mem + (size_t)n_nodes * MEMH;

    const size_t bm_words = (size_t)((n_nodes + 31) / 32);
    const size_t bm_bytes_pad = bm_words * 4 + 16;    // +16B so 2-word window reads are safe
    const bool ws_w  = (d_ws != nullptr) && (ws_size >= W_BYTES);
    const bool ws_bm = (d_ws != nullptr) && (ws_size >= W_BYTES + bm_bytes_pad);

    short*    wsw = (short*)d_ws;
    unsigned* bm  = (unsigned*)((char*)d_ws + W_BYTES);

    if (ws_w) {
        smu_cvtw_kernel<<<(W_TOT_ELEMS + 255) / 256, 256, 0, stream>>>(Wih, Whh, wsw);
    }
    if (ws_bm) {
        (void)hipMemsetAsync(bm, 0, bm_bytes_pad, stream);
        smu_bits_kernel<<<(n_upd + 255) / 256, 256, 0, stream>>>(ids, bm, n_upd);
    }

    const int  grid   = n_upd / BM;   // 65536/64 = 1024
    const long cpslab = (n_nodes + grid - 1) / grid;   // 489

    if (ws_bm) {
        smu_gru_kernel<true, true><<<grid, NTHR, 0, stream>>>(
            ids, msg, ts, mem, lu, Wih, Whh, bih, bhh, gam, bet,
            wsw, bm, out_mem, out_lu, n_nodes, cpslab);
    } else {
        long n_mem4 = n_nodes * (MEMH / 4);
        long n_lu4  = n_nodes / 4;
        smu_copy_kernel<<<2048, 256, 0, stream>>>(mem, lu, out_mem, out_lu,
                                                  n_mem4, n_lu4);
        if (ws_w) {
            smu_gru_kernel<true, false><<<grid, NTHR, 0, stream>>>(
                ids, msg, ts, mem, lu, Wih, Whh, bih, bhh, gam, bet,
                wsw, nullptr, out_mem, out_lu, n_nodes, cpslab);
        } else {
            smu_gru_kernel<false, false><<<grid, NTHR, 0, stream>>>(
                ids, msg, ts, mem, lu, Wih, Whh, bih, bhh, gam, bet,
                nullptr, nullptr, out_mem, out_lu, n_nodes, cpslab);
        }
    }
}

// Round 6
// 350.760 us; speedup vs baseline: 1.3814x; 1.3814x over previous
//
#include <hip/hip_runtime.h>
#include <hip/hip_bf16.h>

typedef float  f32x4 __attribute__((ext_vector_type(4)));
typedef short  s16x8 __attribute__((ext_vector_type(8)));

#define MEMH   256        // mem_dim
#define MSGD   512        // msg_dim
#define G3     768        // 3*H
#define W_IH_ELEMS (G3*MSGD)        // 393216
#define W_HH_ELEMS (G3*MEMH)        // 196608
#define W_TOT_ELEMS (W_IH_ELEMS + W_HH_ELEMS)  // 589824
#define W_BYTES    ((size_t)W_TOT_ELEMS * 2)   // 1179648

#define BM     64         // rows per block
#define NTHR   1024       // 16 waves
#define AH_OFF 0          // A_h: 64x256 bf16, pitch 512 B  -> 32768 B
#define AM_OFF 32768      // A_msg: 64x512 bf16, pitch 1024 B -> 65536 B
#define O_OFF  32768      // O fp32 64x260 (pitch 1040 B) reuses A_msg region
#define LDS_BYTES (32768 + 66560)   // 99328

static __device__ __forceinline__ short f2bf(float x) {
    __hip_bfloat16 b = __float2bfloat16(x);
    return __builtin_bit_cast(short, b);
}
static __device__ __forceinline__ float bf2f(short s) {
    unsigned int u = ((unsigned int)(unsigned short)s) << 16;
    return __builtin_bit_cast(float, u);
}
static __device__ __forceinline__ float sigf(float x) {
    return 1.f / (1.f + __expf(-x));
}
static __device__ __forceinline__ float tanh_fast(float x) {
    float e = __expf(-2.f * fabsf(x));
    float t = (1.f - e) / (1.f + e);
    return copysignf(t, x);
}
static __device__ __forceinline__ f32x4 ntload4(const float* p) {
    return __builtin_nontemporal_load((const f32x4*)p);
}
static __device__ __forceinline__ void ntstore4(float* p, f32x4 v) {
    __builtin_nontemporal_store(v, (f32x4*)p);
}

// ------------------------------------------------- full copy kernel (fallback)
__global__ void smu_copy_kernel(const float* __restrict__ mem,
                                const float* __restrict__ lu,
                                float* __restrict__ out_mem,
                                float* __restrict__ out_lu,
                                long n_mem4, long n_lu4) {
    long i = (long)blockIdx.x * blockDim.x + threadIdx.x;
    long stride = (long)gridDim.x * blockDim.x;
    long total = n_mem4 + n_lu4;
    for (; i < total; i += stride) {
        if (i < n_mem4) ntstore4(out_mem + i * 4, ntload4(mem + i * 4));
        else {
            long j = (i - n_mem4) * 4;
            ntstore4(out_lu + j, ntload4(lu + j));
        }
    }
}

// --------------------------------------- bitmap-skipping copy kernel (main path)
// 16B units; 64 units per 1KB memory row. 4-deep load/store batches per thread.
__global__ __launch_bounds__(256)
void smu_copy_skip_kernel(const float* __restrict__ mem,
                          const float* __restrict__ lu,
                          const unsigned* __restrict__ bm,
                          float* __restrict__ out_mem,
                          float* __restrict__ out_lu,
                          long n_nodes) {
    const long nu = n_nodes * (MEMH / 4);                 // 32,000,000 units
    const long stride = (long)gridDim.x * blockDim.x;     // 524,288
    const long i0 = (long)blockIdx.x * blockDim.x + threadIdx.x;

    for (long i = i0; i < nu; i += stride * 4) {
        long  u0 = i, u1 = i + stride, u2 = i + stride * 2, u3 = i + stride * 3;
        f32x4 v0, v1, v2, v3;
        bool  f0 = false, f1 = false, f2 = false, f3 = false;
        {
            long r = u0 >> 6;
            f0 = !((bm[r >> 5] >> (r & 31)) & 1u);
            if (f0) v0 = ntload4(mem + u0 * 4);
        }
        if (u1 < nu) {
            long r = u1 >> 6;
            f1 = !((bm[r >> 5] >> (r & 31)) & 1u);
            if (f1) v1 = ntload4(mem + u1 * 4);
        }
        if (u2 < nu) {
            long r = u2 >> 6;
            f2 = !((bm[r >> 5] >> (r & 31)) & 1u);
            if (f2) v2 = ntload4(mem + u2 * 4);
        }
        if (u3 < nu) {
            long r = u3 >> 6;
            f3 = !((bm[r >> 5] >> (r & 31)) & 1u);
            if (f3) v3 = ntload4(mem + u3 * 4);
        }
        if (f0) ntstore4(out_mem + u0 * 4, v0);
        if (f1) ntstore4(out_mem + u1 * 4, v1);
        if (f2) ntstore4(out_mem + u2 * 4, v2);
        if (f3) ntstore4(out_mem + u3 * 4, v3);
    }
    // last_update (2 MB): scalar, bitmap-guarded
    for (long i = i0; i < n_nodes; i += stride) {
        if (!((bm[i >> 5] >> (i & 31)) & 1u)) {
            float v = __builtin_nontemporal_load(lu + i);
            __builtin_nontemporal_store(v, out_lu + i);
        }
    }
}

// --------------------------------------------------- weight fp32->bf16 PACKED fragment layout
// ih: frag (t in [0,48), k in [0,16)) at elem off (t*16+k)*512; within frag
// elem idx = l*8+e  ->  source row t*16+(l&15), col k*32+(l>>4)*8+e.
// hh: frag (t in [0,48), k in [0,8)) at W_IH_ELEMS + (t*8+k)*512, same inner map.
__global__ void smu_cvtw_kernel(const float* __restrict__ wih,
                                const float* __restrict__ whh,
                                short* __restrict__ o) {
    int i = blockIdx.x * blockDim.x + threadIdx.x;
    if (i >= W_TOT_ELEMS) return;
    if (i < W_IH_ELEMS) {
        int f = i >> 9, r = i & 511, l = r >> 3, e = r & 7;
        int t = f >> 4, k = f & 15;
        int row = t * 16 + (l & 15), col = k * 32 + (l >> 4) * 8 + e;
        o[i] = f2bf(wih[row * MSGD + col]);
    } else {
        int j = i - W_IH_ELEMS;
        int f = j >> 9, r = j & 511, l = r >> 3, e = r & 7;
        int t = f >> 3, k = f & 7;
        int row = t * 16 + (l & 15), col = k * 32 + (l >> 4) * 8 + e;
        o[i] = f2bf(whh[row * MEMH + col]);
    }
}

// --------------------------------------------------- bitmap of updated ids
__global__ void smu_bits_kernel(const int* __restrict__ ids,
                                unsigned* __restrict__ bm, int n) {
    int i = blockIdx.x * blockDim.x + threadIdx.x;
    if (i < n) {
        int id = ids[i];
        atomicOr(&bm[id >> 5], 1u << (id & 31));
    }
}

// ------------------------------------------------------------ B-frag loader
// packed path: one contiguous 1KB wave load. fallback: scattered f32 converts.
template<bool USE_WS>
static __device__ __forceinline__ s16x8 load_b(const float* __restrict__ Wf,
                                               const short* __restrict__ Wb,
                                               int t, int k, int ldk, int nkt, int lane) {
    if constexpr (USE_WS) {
        return *(const s16x8*)(Wb + ((size_t)(t * nkt + k) << 9) + lane * 8);
    } else {
        int row = t * 16 + (lane & 15);
        int col = k * 32 + (lane >> 4) * 8;
        f32x4 x = *(const f32x4*)(Wf + (size_t)row * ldk + col);
        f32x4 y = *(const f32x4*)(Wf + (size_t)row * ldk + col + 4);
        s16x8 s;
        s[0]=f2bf(x[0]); s[1]=f2bf(x[1]); s[2]=f2bf(x[2]); s[3]=f2bf(x[3]);
        s[4]=f2bf(y[0]); s[5]=f2bf(y[1]); s[6]=f2bf(y[2]); s[7]=f2bf(y[3]);
        return s;
    }
}

// --------------------------------------------------------------- fused GRU+LN
// Block: 1024 threads (16 waves), BM=64 rows. Wave w owns gate-tiles
// t = w+16i (i = r,z,n). Accs: acc[m][0]=r-sum, acc[m][1]=z-sum,
// acc[m][2]=gi_n, accn[m]=gh_n  (GEMM2 adds r,z into acc[m][0..1]).
template<bool USE_WS>
__global__ __launch_bounds__(NTHR, 1)
void smu_gru_kernel(const int*   __restrict__ ids,
                    const float* __restrict__ msg,
                    const float* __restrict__ ts,
                    const float* __restrict__ memory,
                    const float* __restrict__ W_ih,
                    const float* __restrict__ W_hh,
                    const float* __restrict__ b_ih,
                    const float* __restrict__ b_hh,
                    const float* __restrict__ gamma,
                    const float* __restrict__ beta,
                    const short* __restrict__ wsw,
                    float* __restrict__ out_mem,
                    float* __restrict__ out_lu) {
    __shared__ __align__(16) unsigned char lds[LDS_BYTES];
    const int tid  = threadIdx.x;
    const int bid  = blockIdx.x;
    const long base = (long)bid * BM;

    // ---- stage A_msg: 64x512 f32 -> bf16 (4096 8-elem units, 4/thread)
    {
        const float* src = msg + base * MSGD;
        #pragma unroll
        for (int it = 0; it < 4; ++it) {
            int u = tid + NTHR * it;         // 0..4095
            int row = u >> 6;                // 64 units per row
            f32x4 a = ntload4(src + u * 8);
            f32x4 b = ntload4(src + u * 8 + 4);
            s16x8 s;
            s[0]=f2bf(a[0]); s[1]=f2bf(a[1]); s[2]=f2bf(a[2]); s[3]=f2bf(a[3]);
            s[4]=f2bf(b[0]); s[5]=f2bf(b[1]); s[6]=f2bf(b[2]); s[7]=f2bf(b[3]);
            int byte = AM_OFF + ((u * 16) ^ ((row & 7) << 4));
            *(s16x8*)(lds + byte) = s;
        }
        // ---- stage A_h (gather): 64x256 (2048 units, 2/thread)
        #pragma unroll
        for (int it = 0; it < 2; ++it) {
            int u = tid + NTHR * it;         // 0..2047
            int row = u >> 5;                // 32 units per row
            int c8  = u & 31;
            int id  = ids[base + row];
            const float* hs = memory + (size_t)id * MEMH + c8 * 8;
            f32x4 a = ntload4(hs);
            f32x4 b = ntload4(hs + 4);
            s16x8 s;
            s[0]=f2bf(a[0]); s[1]=f2bf(a[1]); s[2]=f2bf(a[2]); s[3]=f2bf(a[3]);
            s[4]=f2bf(b[0]); s[5]=f2bf(b[1]); s[6]=f2bf(b[2]); s[7]=f2bf(b[3]);
            int byte = AH_OFF + ((u * 16) ^ ((row & 7) << 4));
            *(s16x8*)(lds + byte) = s;
        }
    }
    __syncthreads();

    const int lane = tid & 63;
    const int w    = tid >> 6;              // 0..15
    const int lr   = lane & 15;
    const int lk8  = (lane >> 4) * 8;       // k offset within 32-wide ktile
    const int sw   = (lr & 7) << 4;
    const short* Wi = wsw;
    const short* Wh = wsw + W_IH_ELEMS;

    f32x4 acc[4][3] = {};   // [m][0]=r-sum  [1]=z-sum  [2]=gi_n
    f32x4 accn[4]   = {};   // gh_n

    // ---- GEMM 1: msg @ W_ih^T  (K=512, 16 ktiles, depth-2 B prefetch)
    {
        s16x8 b[2][3];
        #pragma unroll
        for (int i = 0; i < 3; ++i) b[0][i] = load_b<USE_WS>(W_ih, Wi, w + 16*i, 0, MSGD, 16, lane);
        #pragma unroll
        for (int i = 0; i < 3; ++i) b[1][i] = load_b<USE_WS>(W_ih, Wi, w + 16*i, 1, MSGD, 16, lane);
        #pragma unroll
        for (int k = 0; k < 16; ++k) {
            const int cb = (k * 32 + lk8) * 2;
            #pragma unroll
            for (int m = 0; m < 4; ++m) {
                s16x8 a = *(const s16x8*)(lds + AM_OFF + (((m*16 + lr) * 1024 + cb) ^ sw));
                #pragma unroll
                for (int i = 0; i < 3; ++i)
                    acc[m][i] = __builtin_amdgcn_mfma_f32_16x16x32_bf16(a, b[k & 1][i], acc[m][i], 0, 0, 0);
            }
            if (k < 14) {
                #pragma unroll
                for (int i = 0; i < 3; ++i)
                    b[k & 1][i] = load_b<USE_WS>(W_ih, Wi, w + 16*i, k + 2, MSGD, 16, lane);
            }
        }
    }
    // ---- GEMM 2: h @ W_hh^T  (K=256, 8 ktiles)
    {
        s16x8 b[2][3];
        #pragma unroll
        for (int i = 0; i < 3; ++i) b[0][i] = load_b<USE_WS>(W_hh, Wh, w + 16*i, 0, MEMH, 8, lane);
        #pragma unroll
        for (int i = 0; i < 3; ++i) b[1][i] = load_b<USE_WS>(W_hh, Wh, w + 16*i, 1, MEMH, 8, lane);
        #pragma unroll
        for (int k = 0; k < 8; ++k) {
            const int cb = (k * 32 + lk8) * 2;
            #pragma unroll
            for (int m = 0; m < 4; ++m) {
                s16x8 a = *(const s16x8*)(lds + AH_OFF + (((m*16 + lr) * 512 + cb) ^ sw));
                acc[m][0] = __builtin_amdgcn_mfma_f32_16x16x32_bf16(a, b[k & 1][0], acc[m][0], 0, 0, 0);
                acc[m][1] = __builtin_amdgcn_mfma_f32_16x16x32_bf16(a, b[k & 1][1], acc[m][1], 0, 0, 0);
                accn[m]   = __builtin_amdgcn_mfma_f32_16x16x32_bf16(a, b[k & 1][2], accn[m],   0, 0, 0);
            }
            if (k < 6) {
                #pragma unroll
                for (int i = 0; i < 3; ++i)
                    b[k & 1][i] = load_b<USE_WS>(W_hh, Wh, w + 16*i, k + 2, MEMH, 8, lane);
            }
        }
    }

    __syncthreads();   // all A_msg reads done before O overwrites region

    // ---- gate epilogue: C layout col=lane&15, row=(lane>>4)*4+q
    {
        const int lq = (lane >> 4) * 4;
        const int j  = w * 16 + lr;          // this lane's output column
        const float br = b_ih[j]       + b_hh[j];
        const float bz = b_ih[256 + j] + b_hh[256 + j];
        const float bihn = b_ih[512 + j], bhhn = b_hh[512 + j];
        #pragma unroll
        for (int m = 0; m < 4; ++m) {
            #pragma unroll
            for (int q = 0; q < 4; ++q) {
                int row = m * 16 + lq + q;
                float r = sigf(acc[m][0][q] + br);
                float z = sigf(acc[m][1][q] + bz);
                float n = tanh_fast(acc[m][2][q] + bihn + r * (accn[m][q] + bhhn));
                float hv = bf2f(*(const short*)(lds + AH_OFF + ((row * 512 + j * 2) ^ ((row & 7) << 4))));
                float o = (1.f - z) * n + z * hv;
                *(float*)(lds + O_OFF + (row * 260 + j) * 4) = o;
            }
        }
    }
    __syncthreads();

    // ---- LayerNorm + scatter: wave w handles rows 4w..4w+3
    #pragma unroll
    for (int rr = 0; rr < 4; ++rr) {
        int row = w * 4 + rr;
        f32x4 x = *(const f32x4*)(lds + O_OFF + (row * 260 + lane * 4) * 4);
        float s1 = x[0] + x[1] + x[2] + x[3];
        float s2 = x[0]*x[0] + x[1]*x[1] + x[2]*x[2] + x[3]*x[3];
        #pragma unroll
        for (int mm = 32; mm > 0; mm >>= 1) {
            s1 += __shfl_xor(s1, mm);
            s2 += __shfl_xor(s2, mm);
        }
        float mu  = s1 * (1.f / 256.f);
        float var = fmaxf(s2 * (1.f / 256.f) - mu * mu, 0.f);
        float inv = rsqrtf(var + 1e-5f);
        f32x4 g  = *(const f32x4*)(gamma + lane * 4);
        f32x4 be = *(const f32x4*)(beta  + lane * 4);
        int id = ids[base + row];
        f32x4 y;
        #pragma unroll
        for (int c = 0; c < 4; ++c) y[c] = (x[c] - mu) * inv * g[c] + be[c];
        ntstore4(out_mem + (size_t)id * MEMH + lane * 4, y);
        if (lane == 0) __builtin_nontemporal_store(ts[base + row], out_lu + id);
    }
}

// ------------------------------------------------------------------- launcher
extern "C" void kernel_launch(void* const* d_in, const int* in_sizes, int n_in,
                              void* d_out, int out_size, void* d_ws, size_t ws_size,
                              hipStream_t stream) {
    (void)n_in; (void)out_size;
    const int*   ids = (const int*)  d_in[0];
    const float* msg = (const float*)d_in[1];
    const float* ts  = (const float*)d_in[2];
    const float* mem = (const float*)d_in[3];
    const float* lu  = (const float*)d_in[4];
    const float* Wih = (const float*)d_in[5];
    const float* Whh = (const float*)d_in[6];
    const float* bih = (const float*)d_in[7];
    const float* bhh = (const float*)d_in[8];
    const float* gam = (const float*)d_in[9];
    const float* bet = (const float*)d_in[10];

    const int  n_upd   = in_sizes[0];                 // 65536
    const long n_nodes = (long)in_sizes[3] / MEMH;    // 500000

    float* out_mem = (float*)d_out;
    float* out_lu  = out_mem + (size_t)n_nodes * MEMH;

    const size_t bm_words = (size_t)((n_nodes + 31) / 32);
    const size_t bm_bytes_pad = bm_words * 4 + 16;
    const bool ws_w  = (d_ws != nullptr) && (ws_size >= W_BYTES);
    const bool ws_bm = (d_ws != nullptr) && (ws_size >= W_BYTES + bm_bytes_pad);

    short*    wsw = (short*)d_ws;
    unsigned* bm  = (unsigned*)((char*)d_ws + W_BYTES);

    const int grid = n_upd / BM;   // 65536/64 = 1024

    if (ws_w) {
        smu_cvtw_kernel<<<(W_TOT_ELEMS + 255) / 256, 256, 0, stream>>>(Wih, Whh, wsw);
    }

    if (ws_bm) {
        (void)hipMemsetAsync(bm, 0, bm_bytes_pad, stream);
        smu_bits_kernel<<<(n_upd + 255) / 256, 256, 0, stream>>>(ids, bm, n_upd);
        // GRU first (weights L2-hot from cvtw), then bitmap-skipped copy.
        smu_gru_kernel<true><<<grid, NTHR, 0, stream>>>(
            ids, msg, ts, mem, Wih, Whh, bih, bhh, gam, bet, wsw, out_mem, out_lu);
        smu_copy_skip_kernel<<<2048, 256, 0, stream>>>(mem, lu, bm, out_mem, out_lu, n_nodes);
    } else {
        // fallback: full copy first, then GRU scatter overwrites updated rows
        long n_mem4 = n_nodes * (MEMH / 4);
        long n_lu4  = n_nodes / 4;
        smu_copy_kernel<<<2048, 256, 0, stream>>>(mem, lu, out_mem, out_lu, n_mem4, n_lu4);
        if (ws_w) {
            smu_gru_kernel<true><<<grid, NTHR, 0, stream>>>(
                ids, msg, ts, mem, Wih, Whh, bih, bhh, gam, bet, wsw, out_mem, out_lu);
        } else {
            smu_gru_kernel<false><<<grid, NTHR, 0, stream>>>(
                ids, msg, ts, mem, Wih, Whh, bih, bhh, gam, bet, nullptr, out_mem, out_lu);
        }
    }
}

// Round 7
// 326.824 us; speedup vs baseline: 1.4826x; 1.0732x over previous
//
#include <hip/hip_runtime.h>
#include <hip/hip_bf16.h>

typedef float  f32x4 __attribute__((ext_vector_type(4)));
typedef short  s16x8 __attribute__((ext_vector_type(8)));

#define MEMH   256        // mem_dim
#define MSGD   512        // msg_dim
#define G3     768        // 3*H
#define W_IH_ELEMS (G3*MSGD)        // 393216
#define W_HH_ELEMS (G3*MEMH)        // 196608
#define W_TOT_ELEMS (W_IH_ELEMS + W_HH_ELEMS)  // 589824
#define W_BYTES    ((size_t)W_TOT_ELEMS * 2)   // 1179648

#define BM     64         // rows per GRU block
#define NTHR   1024       // 16 waves
#define AH_OFF 0          // A_h: 64x256 bf16, pitch 512 B  -> 32768 B
#define AM_OFF 32768      // A_msg: 64x512 bf16, pitch 1024 B -> 65536 B
#define O_OFF  32768      // O fp32 64x260 (pitch 1040 B) reuses A_msg region
#define LDS_BYTES (32768 + 66560)   // 99328

static __device__ __forceinline__ short f2bf(float x) {
    __hip_bfloat16 b = __float2bfloat16(x);
    return __builtin_bit_cast(short, b);
}
static __device__ __forceinline__ float bf2f(short s) {
    unsigned int u = ((unsigned int)(unsigned short)s) << 16;
    return __builtin_bit_cast(float, u);
}
static __device__ __forceinline__ float sigf(float x) {
    return 1.f / (1.f + __expf(-x));
}
static __device__ __forceinline__ float tanh_fast(float x) {
    float e = __expf(-2.f * fabsf(x));
    float t = (1.f - e) / (1.f + e);
    return copysignf(t, x);
}
static __device__ __forceinline__ f32x4 ntload4(const float* p) {
    return __builtin_nontemporal_load((const f32x4*)p);
}
static __device__ __forceinline__ void ntstore4(float* p, f32x4 v) {
    __builtin_nontemporal_store(v, (f32x4*)p);
}

// ------------------------------------------------- full copy kernel (fallback)
__global__ void smu_copy_kernel(const float* __restrict__ mem,
                                const float* __restrict__ lu,
                                float* __restrict__ out_mem,
                                float* __restrict__ out_lu,
                                long n_mem4, long n_lu4) {
    long i = (long)blockIdx.x * blockDim.x + threadIdx.x;
    long stride = (long)gridDim.x * blockDim.x;
    long total = n_mem4 + n_lu4;
    for (; i < total; i += stride) {
        if (i < n_mem4) ntstore4(out_mem + i * 4, ntload4(mem + i * 4));
        else {
            long j = (i - n_mem4) * 4;
            ntstore4(out_lu + j, ntload4(lu + j));
        }
    }
}

// --------------------------------------------------- weight fp32->bf16 PACKED fragment layout
// ih: frag (t in [0,48), k in [0,16)) at elem off (t*16+k)*512; within frag
// elem idx = l*8+e  ->  source row t*16+(l&15), col k*32+(l>>4)*8+e.
// hh: frag (t in [0,48), k in [0,8)) at W_IH_ELEMS + (t*8+k)*512, same inner map.
__global__ void smu_cvtw_kernel(const float* __restrict__ wih,
                                const float* __restrict__ whh,
                                short* __restrict__ o) {
    int i = blockIdx.x * blockDim.x + threadIdx.x;
    if (i >= W_TOT_ELEMS) return;
    if (i < W_IH_ELEMS) {
        int f = i >> 9, r = i & 511, l = r >> 3, e = r & 7;
        int t = f >> 4, k = f & 15;
        int row = t * 16 + (l & 15), col = k * 32 + (l >> 4) * 8 + e;
        o[i] = f2bf(wih[row * MSGD + col]);
    } else {
        int j = i - W_IH_ELEMS;
        int f = j >> 9, r = j & 511, l = r >> 3, e = r & 7;
        int t = f >> 3, k = f & 7;
        int row = t * 16 + (l & 15), col = k * 32 + (l >> 4) * 8 + e;
        o[i] = f2bf(whh[row * MEMH + col]);
    }
}

// --------------------------------------------------- bitmap clear + set
__global__ void smu_clear_kernel(unsigned* __restrict__ p, int n) {
    int i = blockIdx.x * blockDim.x + threadIdx.x;
    if (i < n) p[i] = 0u;
}
__global__ void smu_bits_kernel(const int* __restrict__ ids,
                                unsigned* __restrict__ bm, int n) {
    int i = blockIdx.x * blockDim.x + threadIdx.x;
    if (i < n) {
        int id = ids[i];
        atomicOr(&bm[id >> 5], 1u << (id & 31));
    }
}

// ------------------------------------------------------------ B-frag loader
// packed path: one contiguous 1KB wave load. fallback: scattered f32 converts.
template<bool USE_WS>
static __device__ __forceinline__ s16x8 load_b(const float* __restrict__ Wf,
                                               const short* __restrict__ Wb,
                                               int t, int k, int ldk, int nkt, int lane) {
    if constexpr (USE_WS) {
        return *(const s16x8*)(Wb + ((size_t)(t * nkt + k) << 9) + lane * 8);
    } else {
        int row = t * 16 + (lane & 15);
        int col = k * 32 + (lane >> 4) * 8;
        f32x4 x = *(const f32x4*)(Wf + (size_t)row * ldk + col);
        f32x4 y = *(const f32x4*)(Wf + (size_t)row * ldk + col + 4);
        s16x8 s;
        s[0]=f2bf(x[0]); s[1]=f2bf(x[1]); s[2]=f2bf(x[2]); s[3]=f2bf(x[3]);
        s[4]=f2bf(y[0]); s[5]=f2bf(y[1]); s[6]=f2bf(y[2]); s[7]=f2bf(y[3]);
        return s;
    }
}

// --------------------------------------------------------------- fused kernel
// grid = 2*n_gru_blocks. Even blocks: GRU+LN (BM=64 rows each). Odd blocks:
// bitmap-skipped copy of memory/last_update. Whole-block role divergence;
// row ownership disjoint (bitmap) -> race-free in any execution order.
// Interleaved roles keep HBM saturated by copy blocks while GRU blocks sit
// in latency-bound k-loops on other CUs.
template<bool USE_WS>
__global__ __launch_bounds__(NTHR, 1)
void smu_fused_kernel(const int*   __restrict__ ids,
                      const float* __restrict__ msg,
                      const float* __restrict__ ts,
                      const float* __restrict__ memory,
                      const float* __restrict__ lu,
                      const float* __restrict__ W_ih,
                      const float* __restrict__ W_hh,
                      const float* __restrict__ b_ih,
                      const float* __restrict__ b_hh,
                      const float* __restrict__ gamma,
                      const float* __restrict__ beta,
                      const short* __restrict__ wsw,
                      const unsigned* __restrict__ bm,
                      float* __restrict__ out_mem,
                      float* __restrict__ out_lu,
                      long n_nodes) {
    __shared__ __align__(16) unsigned char lds[LDS_BYTES];
    const int tid = threadIdx.x;
    const int bid = blockIdx.x;

    if (bid & 1) {
        // ================= COPY role =================
        const long nblk   = gridDim.x >> 1;
        const long cid    = bid >> 1;
        const long nu     = n_nodes * (MEMH / 4);           // 16B units
        const long stride = nblk * NTHR;
        const long i0     = cid * NTHR + tid;

        for (long i = i0; i < nu; i += stride * 4) {
            long  u0 = i, u1 = i + stride, u2 = i + stride * 2, u3 = i + stride * 3;
            f32x4 v0, v1, v2, v3;
            bool  f0 = false, f1 = false, f2 = false, f3 = false;
            {
                long r = u0 >> 6;
                f0 = !((bm[r >> 5] >> (r & 31)) & 1u);
                if (f0) v0 = ntload4(memory + u0 * 4);
            }
            if (u1 < nu) {
                long r = u1 >> 6;
                f1 = !((bm[r >> 5] >> (r & 31)) & 1u);
                if (f1) v1 = ntload4(memory + u1 * 4);
            }
            if (u2 < nu) {
                long r = u2 >> 6;
                f2 = !((bm[r >> 5] >> (r & 31)) & 1u);
                if (f2) v2 = ntload4(memory + u2 * 4);
            }
            if (u3 < nu) {
                long r = u3 >> 6;
                f3 = !((bm[r >> 5] >> (r & 31)) & 1u);
                if (f3) v3 = ntload4(memory + u3 * 4);
            }
            if (f0) ntstore4(out_mem + u0 * 4, v0);
            if (f1) ntstore4(out_mem + u1 * 4, v1);
            if (f2) ntstore4(out_mem + u2 * 4, v2);
            if (f3) ntstore4(out_mem + u3 * 4, v3);
        }
        // last_update (2 MB): scalar, bitmap-guarded
        for (long i = i0; i < n_nodes; i += stride) {
            if (!((bm[i >> 5] >> (i & 31)) & 1u)) {
                float v = __builtin_nontemporal_load(lu + i);
                __builtin_nontemporal_store(v, out_lu + i);
            }
        }
        return;
    }

    // ================= GRU role =================
    const long base = (long)(bid >> 1) * BM;

    // ---- stage A_msg: 64x512 f32 -> bf16 (4096 8-elem units, 4/thread)
    {
        const float* src = msg + base * MSGD;
        #pragma unroll
        for (int it = 0; it < 4; ++it) {
            int u = tid + NTHR * it;         // 0..4095
            int row = u >> 6;                // 64 units per row
            f32x4 a = ntload4(src + u * 8);
            f32x4 b = ntload4(src + u * 8 + 4);
            s16x8 s;
            s[0]=f2bf(a[0]); s[1]=f2bf(a[1]); s[2]=f2bf(a[2]); s[3]=f2bf(a[3]);
            s[4]=f2bf(b[0]); s[5]=f2bf(b[1]); s[6]=f2bf(b[2]); s[7]=f2bf(b[3]);
            int byte = AM_OFF + ((u * 16) ^ ((row & 7) << 4));
            *(s16x8*)(lds + byte) = s;
        }
        // ---- stage A_h (gather): 64x256 (2048 units, 2/thread)
        #pragma unroll
        for (int it = 0; it < 2; ++it) {
            int u = tid + NTHR * it;         // 0..2047
            int row = u >> 5;                // 32 units per row
            int c8  = u & 31;
            int id  = ids[base + row];
            const float* hs = memory + (size_t)id * MEMH + c8 * 8;
            f32x4 a = ntload4(hs);
            f32x4 b = ntload4(hs + 4);
            s16x8 s;
            s[0]=f2bf(a[0]); s[1]=f2bf(a[1]); s[2]=f2bf(a[2]); s[3]=f2bf(a[3]);
            s[4]=f2bf(b[0]); s[5]=f2bf(b[1]); s[6]=f2bf(b[2]); s[7]=f2bf(b[3]);
            int byte = AH_OFF + ((u * 16) ^ ((row & 7) << 4));
            *(s16x8*)(lds + byte) = s;
        }
    }
    __syncthreads();

    const int lane = tid & 63;
    const int w    = tid >> 6;              // 0..15
    const int lr   = lane & 15;
    const int lk8  = (lane >> 4) * 8;       // k offset within 32-wide ktile
    const int sw   = (lr & 7) << 4;
    const short* Wi = wsw;
    const short* Wh = wsw + W_IH_ELEMS;

    f32x4 acc[4][3] = {};   // [m][0]=r-sum  [1]=z-sum  [2]=gi_n
    f32x4 accn[4]   = {};   // gh_n

    // ---- GEMM 1: msg @ W_ih^T  (K=512, 16 ktiles, depth-2 B prefetch)
    {
        s16x8 b[2][3];
        #pragma unroll
        for (int i = 0; i < 3; ++i) b[0][i] = load_b<USE_WS>(W_ih, Wi, w + 16*i, 0, MSGD, 16, lane);
        #pragma unroll
        for (int i = 0; i < 3; ++i) b[1][i] = load_b<USE_WS>(W_ih, Wi, w + 16*i, 1, MSGD, 16, lane);
        #pragma unroll
        for (int k = 0; k < 16; ++k) {
            const int cb = (k * 32 + lk8) * 2;
            #pragma unroll
            for (int m = 0; m < 4; ++m) {
                s16x8 a = *(const s16x8*)(lds + AM_OFF + (((m*16 + lr) * 1024 + cb) ^ sw));
                #pragma unroll
                for (int i = 0; i < 3; ++i)
                    acc[m][i] = __builtin_amdgcn_mfma_f32_16x16x32_bf16(a, b[k & 1][i], acc[m][i], 0, 0, 0);
            }
            if (k < 14) {
                #pragma unroll
                for (int i = 0; i < 3; ++i)
                    b[k & 1][i] = load_b<USE_WS>(W_ih, Wi, w + 16*i, k + 2, MSGD, 16, lane);
            }
        }
    }
    // ---- GEMM 2: h @ W_hh^T  (K=256, 8 ktiles)
    {
        s16x8 b[2][3];
        #pragma unroll
        for (int i = 0; i < 3; ++i) b[0][i] = load_b<USE_WS>(W_hh, Wh, w + 16*i, 0, MEMH, 8, lane);
        #pragma unroll
        for (int i = 0; i < 3; ++i) b[1][i] = load_b<USE_WS>(W_hh, Wh, w + 16*i, 1, MEMH, 8, lane);
        #pragma unroll
        for (int k = 0; k < 8; ++k) {
            const int cb = (k * 32 + lk8) * 2;
            #pragma unroll
            for (int m = 0; m < 4; ++m) {
                s16x8 a = *(const s16x8*)(lds + AH_OFF + (((m*16 + lr) * 512 + cb) ^ sw));
                acc[m][0] = __builtin_amdgcn_mfma_f32_16x16x32_bf16(a, b[k & 1][0], acc[m][0], 0, 0, 0);
                acc[m][1] = __builtin_amdgcn_mfma_f32_16x16x32_bf16(a, b[k & 1][1], acc[m][1], 0, 0, 0);
                accn[m]   = __builtin_amdgcn_mfma_f32_16x16x32_bf16(a, b[k & 1][2], accn[m],   0, 0, 0);
            }
            if (k < 6) {
                #pragma unroll
                for (int i = 0; i < 3; ++i)
                    b[k & 1][i] = load_b<USE_WS>(W_hh, Wh, w + 16*i, k + 2, MEMH, 8, lane);
            }
        }
    }

    __syncthreads();   // all A_msg reads done before O overwrites region

    // ---- gate epilogue: C layout col=lane&15, row=(lane>>4)*4+q
    {
        const int lq = (lane >> 4) * 4;
        const int j  = w * 16 + lr;          // this lane's output column
        const float br = b_ih[j]       + b_hh[j];
        const float bz = b_ih[256 + j] + b_hh[256 + j];
        const float bihn = b_ih[512 + j], bhhn = b_hh[512 + j];
        #pragma unroll
        for (int m = 0; m < 4; ++m) {
            #pragma unroll
            for (int q = 0; q < 4; ++q) {
                int row = m * 16 + lq + q;
                float r = sigf(acc[m][0][q] + br);
                float z = sigf(acc[m][1][q] + bz);
                float n = tanh_fast(acc[m][2][q] + bihn + r * (accn[m][q] + bhhn));
                float hv = bf2f(*(const short*)(lds + AH_OFF + ((row * 512 + j * 2) ^ ((row & 7) << 4))));
                float o = (1.f - z) * n + z * hv;
                *(float*)(lds + O_OFF + (row * 260 + j) * 4) = o;
            }
        }
    }
    __syncthreads();

    // ---- LayerNorm + scatter: wave w handles rows 4w..4w+3
    #pragma unroll
    for (int rr = 0; rr < 4; ++rr) {
        int row = w * 4 + rr;
        f32x4 x = *(const f32x4*)(lds + O_OFF + (row * 260 + lane * 4) * 4);
        float s1 = x[0] + x[1] + x[2] + x[3];
        float s2 = x[0]*x[0] + x[1]*x[1] + x[2]*x[2] + x[3]*x[3];
        #pragma unroll
        for (int mm = 32; mm > 0; mm >>= 1) {
            s1 += __shfl_xor(s1, mm);
            s2 += __shfl_xor(s2, mm);
        }
        float mu  = s1 * (1.f / 256.f);
        float var = fmaxf(s2 * (1.f / 256.f) - mu * mu, 0.f);
        float inv = rsqrtf(var + 1e-5f);
        f32x4 g  = *(const f32x4*)(gamma + lane * 4);
        f32x4 be = *(const f32x4*)(beta  + lane * 4);
        int id = ids[base + row];
        f32x4 y;
        #pragma unroll
        for (int c = 0; c < 4; ++c) y[c] = (x[c] - mu) * inv * g[c] + be[c];
        ntstore4(out_mem + (size_t)id * MEMH + lane * 4, y);
        if (lane == 0) __builtin_nontemporal_store(ts[base + row], out_lu + id);
    }
}

// --------------------------------------------------------------- GRU-only (fallback)
template<bool USE_WS>
__global__ __launch_bounds__(NTHR, 1)
void smu_gru_kernel(const int*   __restrict__ ids,
                    const float* __restrict__ msg,
                    const float* __restrict__ ts,
                    const float* __restrict__ memory,
                    const float* __restrict__ W_ih,
                    const float* __restrict__ W_hh,
                    const float* __restrict__ b_ih,
                    const float* __restrict__ b_hh,
                    const float* __restrict__ gamma,
                    const float* __restrict__ beta,
                    const short* __restrict__ wsw,
                    float* __restrict__ out_mem,
                    float* __restrict__ out_lu) {
    __shared__ __align__(16) unsigned char lds[LDS_BYTES];
    const int tid = threadIdx.x;
    const long base = (long)blockIdx.x * BM;

    {
        const float* src = msg + base * MSGD;
        #pragma unroll
        for (int it = 0; it < 4; ++it) {
            int u = tid + NTHR * it;
            int row = u >> 6;
            f32x4 a = ntload4(src + u * 8);
            f32x4 b = ntload4(src + u * 8 + 4);
            s16x8 s;
            s[0]=f2bf(a[0]); s[1]=f2bf(a[1]); s[2]=f2bf(a[2]); s[3]=f2bf(a[3]);
            s[4]=f2bf(b[0]); s[5]=f2bf(b[1]); s[6]=f2bf(b[2]); s[7]=f2bf(b[3]);
            int byte = AM_OFF + ((u * 16) ^ ((row & 7) << 4));
            *(s16x8*)(lds + byte) = s;
        }
        #pragma unroll
        for (int it = 0; it < 2; ++it) {
            int u = tid + NTHR * it;
            int row = u >> 5;
            int c8  = u & 31;
            int id  = ids[base + row];
            const float* hs = memory + (size_t)id * MEMH + c8 * 8;
            f32x4 a = ntload4(hs);
            f32x4 b = ntload4(hs + 4);
            s16x8 s;
            s[0]=f2bf(a[0]); s[1]=f2bf(a[1]); s[2]=f2bf(a[2]); s[3]=f2bf(a[3]);
            s[4]=f2bf(b[0]); s[5]=f2bf(b[1]); s[6]=f2bf(b[2]); s[7]=f2bf(b[3]);
            int byte = AH_OFF + ((u * 16) ^ ((row & 7) << 4));
            *(s16x8*)(lds + byte) = s;
        }
    }
    __syncthreads();

    const int lane = tid & 63;
    const int w    = tid >> 6;
    const int lr   = lane & 15;
    const int lk8  = (lane >> 4) * 8;
    const int sw   = (lr & 7) << 4;
    const short* Wi = wsw;
    const short* Wh = wsw + W_IH_ELEMS;

    f32x4 acc[4][3] = {};
    f32x4 accn[4]   = {};

    {
        s16x8 b[2][3];
        #pragma unroll
        for (int i = 0; i < 3; ++i) b[0][i] = load_b<USE_WS>(W_ih, Wi, w + 16*i, 0, MSGD, 16, lane);
        #pragma unroll
        for (int i = 0; i < 3; ++i) b[1][i] = load_b<USE_WS>(W_ih, Wi, w + 16*i, 1, MSGD, 16, lane);
        #pragma unroll
        for (int k = 0; k < 16; ++k) {
            const int cb = (k * 32 + lk8) * 2;
            #pragma unroll
            for (int m = 0; m < 4; ++m) {
                s16x8 a = *(const s16x8*)(lds + AM_OFF + (((m*16 + lr) * 1024 + cb) ^ sw));
                #pragma unroll
                for (int i = 0; i < 3; ++i)
                    acc[m][i] = __builtin_amdgcn_mfma_f32_16x16x32_bf16(a, b[k & 1][i], acc[m][i], 0, 0, 0);
            }
            if (k < 14) {
                #pragma unroll
                for (int i = 0; i < 3; ++i)
                    b[k & 1][i] = load_b<USE_WS>(W_ih, Wi, w + 16*i, k + 2, MSGD, 16, lane);
            }
        }
    }
    {
        s16x8 b[2][3];
        #pragma unroll
        for (int i = 0; i < 3; ++i) b[0][i] = load_b<USE_WS>(W_hh, Wh, w + 16*i, 0, MEMH, 8, lane);
        #pragma unroll
        for (int i = 0; i < 3; ++i) b[1][i] = load_b<USE_WS>(W_hh, Wh, w + 16*i, 1, MEMH, 8, lane);
        #pragma unroll
        for (int k = 0; k < 8; ++k) {
            const int cb = (k * 32 + lk8) * 2;
            #pragma unroll
            for (int m = 0; m < 4; ++m) {
                s16x8 a = *(const s16x8*)(lds + AH_OFF + (((m*16 + lr) * 512 + cb) ^ sw));
                acc[m][0] = __builtin_amdgcn_mfma_f32_16x16x32_bf16(a, b[k & 1][0], acc[m][0], 0, 0, 0);
                acc[m][1] = __builtin_amdgcn_mfma_f32_16x16x32_bf16(a, b[k & 1][1], acc[m][1], 0, 0, 0);
                accn[m]   = __builtin_amdgcn_mfma_f32_16x16x32_bf16(a, b[k & 1][2], accn[m],   0, 0, 0);
            }
            if (k < 6) {
                #pragma unroll
                for (int i = 0; i < 3; ++i)
                    b[k & 1][i] = load_b<USE_WS>(W_hh, Wh, w + 16*i, k + 2, MEMH, 8, lane);
            }
        }
    }

    __syncthreads();

    {
        const int lq = (lane >> 4) * 4;
        const int j  = w * 16 + lr;
        const float br = b_ih[j]       + b_hh[j];
        const float bz = b_ih[256 + j] + b_hh[256 + j];
        const float bihn = b_ih[512 + j], bhhn = b_hh[512 + j];
        #pragma unroll
        for (int m = 0; m < 4; ++m) {
            #pragma unroll
            for (int q = 0; q < 4; ++q) {
                int row = m * 16 + lq + q;
                float r = sigf(acc[m][0][q] + br);
                float z = sigf(acc[m][1][q] + bz);
                float n = tanh_fast(acc[m][2][q] + bihn + r * (accn[m][q] + bhhn));
                float hv = bf2f(*(const short*)(lds + AH_OFF + ((row * 512 + j * 2) ^ ((row & 7) << 4))));
                float o = (1.f - z) * n + z * hv;
                *(float*)(lds + O_OFF + (row * 260 + j) * 4) = o;
            }
        }
    }
    __syncthreads();

    #pragma unroll
    for (int rr = 0; rr < 4; ++rr) {
        int row = w * 4 + rr;
        f32x4 x = *(const f32x4*)(lds + O_OFF + (row * 260 + lane * 4) * 4);
        float s1 = x[0] + x[1] + x[2] + x[3];
        float s2 = x[0]*x[0] + x[1]*x[1] + x[2]*x[2] + x[3]*x[3];
        #pragma unroll
        for (int mm = 32; mm > 0; mm >>= 1) {
            s1 += __shfl_xor(s1, mm);
            s2 += __shfl_xor(s2, mm);
        }
        float mu  = s1 * (1.f / 256.f);
        float var = fmaxf(s2 * (1.f / 256.f) - mu * mu, 0.f);
        float inv = rsqrtf(var + 1e-5f);
        f32x4 g  = *(const f32x4*)(gamma + lane * 4);
        f32x4 be = *(const f32x4*)(beta  + lane * 4);
        int id = ids[base + row];
        f32x4 y;
        #pragma unroll
        for (int c = 0; c < 4; ++c) y[c] = (x[c] - mu) * inv * g[c] + be[c];
        ntstore4(out_mem + (size_t)id * MEMH + lane * 4, y);
        if (lane == 0) __builtin_nontemporal_store(ts[base + row], out_lu + id);
    }
}

// ------------------------------------------------------------------- launcher
extern "C" void kernel_launch(void* const* d_in, const int* in_sizes, int n_in,
                              void* d_out, int out_size, void* d_ws, size_t ws_size,
                              hipStream_t stream) {
    (void)n_in; (void)out_size;
    const int*   ids = (const int*)  d_in[0];
    const float* msg = (const float*)d_in[1];
    const float* ts  = (const float*)d_in[2];
    const float* mem = (const float*)d_in[3];
    const float* lu  = (const float*)d_in[4];
    const float* Wih = (const float*)d_in[5];
    const float* Whh = (const float*)d_in[6];
    const float* bih = (const float*)d_in[7];
    const float* bhh = (const float*)d_in[8];
    const float* gam = (const float*)d_in[9];
    const float* bet = (const float*)d_in[10];

    const int  n_upd   = in_sizes[0];                 // 65536
    const long n_nodes = (long)in_sizes[3] / MEMH;    // 500000

    float* out_mem = (float*)d_out;
    float* out_lu  = out_mem + (size_t)n_nodes * MEMH;

    const int    bm_words     = (int)((n_nodes + 31) / 32) + 4;   // padded
    const size_t bm_bytes_pad = (size_t)bm_words * 4;
    const bool ws_w  = (d_ws != nullptr) && (ws_size >= W_BYTES);
    const bool ws_bm = (d_ws != nullptr) && (ws_size >= W_BYTES + bm_bytes_pad);

    short*    wsw = (short*)d_ws;
    unsigned* bm  = (unsigned*)((char*)d_ws + W_BYTES);

    const int grid = n_upd / BM;   // 65536/64 = 1024

    if (ws_w) {
        smu_cvtw_kernel<<<(W_TOT_ELEMS + 255) / 256, 256, 0, stream>>>(Wih, Whh, wsw);
    }

    if (ws_bm) {
        smu_clear_kernel<<<(bm_words + 255) / 256, 256, 0, stream>>>(bm, bm_words);
        smu_bits_kernel<<<(n_upd + 255) / 256, 256, 0, stream>>>(ids, bm, n_upd);
        // single fused dispatch: even blocks GRU, odd blocks bitmap-skipped copy
        smu_fused_kernel<true><<<2 * grid, NTHR, 0, stream>>>(
            ids, msg, ts, mem, lu, Wih, Whh, bih, bhh, gam, bet,
            wsw, bm, out_mem, out_lu, n_nodes);
    } else {
        // fallback: full copy first, then GRU scatter overwrites updated rows
        long n_mem4 = n_nodes * (MEMH / 4);
        long n_lu4  = n_nodes / 4;
        smu_copy_kernel<<<2048, 256, 0, stream>>>(mem, lu, out_mem, out_lu, n_mem4, n_lu4);
        if (ws_w) {
            smu_gru_kernel<true><<<grid, NTHR, 0, stream>>>(
                ids, msg, ts, mem, Wih, Whh, bih, bhh, gam, bet, wsw, out_mem, out_lu);
        } else {
            smu_gru_kernel<false><<<grid, NTHR, 0, stream>>>(
                ids, msg, ts, mem, Wih, Whh, bih, bhh, gam, bet, nullptr, out_mem, out_lu);
        }
    }
}